// Round 7
// baseline (469.547 us; speedup 1.0000x reference)
//
#include <hip/hip_runtime.h>
#include <hip/hip_bf16.h>

#define PW 64
#define NV 512
#define HW 256
#define COV 16
#define BATCH 2048
#define XROW (PW * NV + COV)   // 32784
#define IMG 16384              // W1 image: 256 n x 64 k shorts (32 KB), slot = g ^ (n&7)
#define IMG2 8192              // W2 image: 256 n x 32 k shorts (16 KB), slot = g ^ ((n>>1)&3)

typedef short s16x8 __attribute__((ext_vector_type(8)));
typedef float f32x4 __attribute__((ext_vector_type(4)));

__device__ __forceinline__ unsigned short f2bf(float f) {
    union { float f; unsigned int u; } v;
    v.f = f;
    unsigned int u = v.u;
    unsigned int r = (u + 0x7fffu + ((u >> 16) & 1u)) >> 16;   // RNE
    return (unsigned short)r;
}

__device__ __forceinline__ unsigned int pack2(float a, float b) {
    __hip_bfloat162 h = __float22bfloat162_rn(float2{a, b});
    union { __hip_bfloat162 h; unsigned int u; } c;
    c.h = h;
    return c.u;
}

__device__ __forceinline__ float lrelu(float v) { return v >= 0.f ? v : 0.2f * v; }

__device__ __forceinline__ void gl_lds16(const void* g, void* l) {
    __builtin_amdgcn_global_load_lds(
        (const __attribute__((address_space(1))) void*)g,
        (__attribute__((address_space(3))) void*)l, 16, 0, 0);
}

#define WAITV(n) asm volatile("s_waitcnt vmcnt(" #n ") lgkmcnt(0)" ::: "memory")
#define BAR()    __builtin_amdgcn_s_barrier()
#define SCHED0() __builtin_amdgcn_sched_barrier(0)

// ---------------------------------------------------------------------------
// Weight prep (as R6) + zero-init of the fused stats accumulators.
// ---------------------------------------------------------------------------
__global__ __launch_bounds__(256)
void transpose_all(const float* __restrict__ W1, const float* __restrict__ W2,
                   unsigned short* __restrict__ W1I, unsigned short* __restrict__ W2I,
                   float* __restrict__ accbuf) {
    __shared__ float tile[64][260];
    int bx = blockIdx.x;
    const int t = threadIdx.x;
    if (bx == 0 && t < 128) accbuf[t] = 0.f;     // sacc[64] + qacc[64]
    const bool isW1 = bx < 512;
    const float* src;
    if (isW1) {
        int p = bx >> 3, kb = bx & 7;
        src = W1 + ((size_t)p * NV + kb * 64) * HW;
    } else {
        int b2 = bx - 512;
        int p = b2 >> 2, kb64 = b2 & 3;
        src = W2 + ((size_t)p * HW + kb64 * 64) * HW;
    }
    #pragma unroll
    for (int i = 0; i < 16; ++i) {
        int idx = t + i * 256;
        int r = idx >> 6, c4 = (idx & 63) << 2;
        *(float4*)&tile[r][c4] = *(const float4*)(src + (size_t)r * HW + c4);
    }
    __syncthreads();
    if (isW1) {
        int p = bx >> 3, kb = bx & 7;
        unsigned short* dst = W1I + (size_t)(p * 8 + kb) * IMG;
        #pragma unroll
        for (int pass = 0; pass < 8; ++pass) {
            int idx = pass * 256 + t;
            int n = idx >> 3, s = idx & 7;
            int g = s ^ (n & 7);
            unsigned short v[8];
            #pragma unroll
            for (int j = 0; j < 8; ++j)
                v[j] = f2bf(tile[g * 8 + j][n]);
            *(s16x8*)(dst + (size_t)idx * 8) = *(s16x8*)v;
        }
    } else {
        int b2 = bx - 512;
        int p = b2 >> 2, kb64 = b2 & 3;
        unsigned short* dst = W2I + (size_t)(p * 8 + kb64 * 2) * IMG2;
        #pragma unroll
        for (int pass = 0; pass < 8; ++pass) {
            int idx = pass * 256 + t;
            int h = idx >> 10;
            int rem = idx & 1023;
            int n = rem >> 2, s = rem & 3;
            int g = s ^ ((n >> 1) & 3);
            int krow = h * 32 + g * 8;
            unsigned short v[8];
            #pragma unroll
            for (int j = 0; j < 8; ++j)
                v[j] = f2bf(tile[krow + j][n]);
            *(s16x8*)(dst + (size_t)h * IMG2 + n * 32 + s * 8) = *(s16x8*)v;
        }
    }
}

// ---------------------------------------------------------------------------
// FULLY-FUSED pathway kernel, BM=256, 512 thr (8 waves = 2m x 4n).
// R7 changes vs R6: (1) APACK/XLOAD moved POST-MFMA so their implicit vmcnt
// waits land after the MFMA cluster (loads get ~1.8 steps of coverage);
// (2) Bs ring-of-3 (2-step weight prefetch); (3) stats fused into epilogue.
// LDS arena 160 KB (1 block/CU):
//   stage A: Bs ring 3x32K [0:96K), As dbuf 2x32K [96K:160K)
//   stage B: H1t 128K [0:128K) (overlay), W2 dbuf 2x16K [128K:160K) (=As buf1)
// ---------------------------------------------------------------------------
__global__ __launch_bounds__(512, 2)
void pathway_fused(const float* __restrict__ x, const unsigned short* __restrict__ W1I,
                   const unsigned short* __restrict__ W2I, const float* __restrict__ W3,
                   float* __restrict__ pvec, float* __restrict__ accbuf) {
    __shared__ __align__(16) unsigned short lds[81920];   // 160 KB arena

    const int lin = blockIdx.x;            // 0..511
    const int xcd = lin & 7;
    const int idx = lin >> 3;              // 0..63
    const int p   = xcd * 8 + (idx >> 3);  // each XCD owns 8 whole pathways
    const int mt  = idx & 7;
    const int bm0 = mt * 256;

    const int t = threadIdx.x;
    const int lane = t & 63;
    const int wave = t >> 6;       // 0..7
    const int wm   = wave >> 2;    // 0..1  (row half)
    const int wn   = wave & 3;     // 0..3  (64-col slice)
    const int l15  = lane & 15;
    const int quad = lane >> 4;

    const float* Ap          = x   + (size_t)p * NV;
    const unsigned short* B1 = W1I + (size_t)p * 8 * IMG;
    const unsigned short* B2 = W2I + (size_t)p * 8 * IMG2;

    int arow[8], acolc[8], aoff[8];
    #pragma unroll
    for (int i = 0; i < 8; ++i) {
        int ii = t + i * 512;          // 0..4095
        arow[i]  = ii >> 4;            // 0..255
        acolc[i] = (ii & 15) * 4;      // 0..60
        int slot = (acolc[i] >> 3) ^ (arow[i] & 7);
        aoff[i]  = arow[i] * 64 + slot * 8 + (acolc[i] & 7);
    }

    float4 S[8];
    f32x4 acc[8][4] = {};

#define XLOAD(k0) { \
    _Pragma("unroll") \
    for (int i = 0; i < 8; ++i) \
        S[i] = *(const float4*)(Ap + (size_t)(bm0 + arow[i]) * XROW + (k0) + acolc[i]); }

#define APACK(buf) { \
    unsigned short* Asb = lds + 49152 + (buf) * 16384; \
    _Pragma("unroll") \
    for (int i = 0; i < 8; ++i) { \
        uint2 u; \
        u.x = pack2(S[i].x, S[i].y); \
        u.y = pack2(S[i].z, S[i].w); \
        *(uint2*)&Asb[aoff[i]] = u; } }

#define B1STAGE(buf, kb) { \
    const unsigned short* img = B1 + (size_t)(kb) * IMG; \
    _Pragma("unroll") \
    for (int c = 0; c < 4; ++c) { \
        int off = wave * 4096 + c * 1024; \
        gl_lds16((const char*)img + off + lane * 16, \
                 (char*)lds + (buf) * 32768 + off); } }

#define MFMA_A(abuf, bbuf) { \
    const unsigned short* Asb = lds + 49152 + (abuf) * 16384; \
    const unsigned short* Bsb = lds + (bbuf) * 16384; \
    __builtin_amdgcn_s_setprio(1); \
    _Pragma("unroll") \
    for (int kk = 0; kk < 64; kk += 32) { \
        s16x8 af[8], bfr[4]; \
        _Pragma("unroll") \
        for (int mi = 0; mi < 8; ++mi) { \
            int row = wm * 128 + mi * 16 + l15; \
            int slot = ((kk >> 3) + quad) ^ (row & 7); \
            af[mi] = *(const s16x8*)&Asb[row * 64 + slot * 8]; } \
        _Pragma("unroll") \
        for (int ni = 0; ni < 4; ++ni) { \
            int row = wn * 64 + ni * 16 + l15; \
            int slot = ((kk >> 3) + quad) ^ (row & 7); \
            bfr[ni] = *(const s16x8*)&Bsb[row * 64 + slot * 8]; } \
        _Pragma("unroll") \
        for (int mi = 0; mi < 8; ++mi) \
            _Pragma("unroll") \
            for (int ni = 0; ni < 4; ++ni) \
                acc[mi][ni] = __builtin_amdgcn_mfma_f32_16x16x32_bf16( \
                    af[mi], bfr[ni], acc[mi][ni], 0, 0, 0); } \
    __builtin_amdgcn_s_setprio(0); }

#define W2STAGE(buf, kb) { \
    const unsigned short* img = B2 + (size_t)(kb) * IMG2; \
    _Pragma("unroll") \
    for (int c = 0; c < 2; ++c) { \
        int off = wave * 2048 + c * 1024; \
        gl_lds16((const char*)img + off + lane * 16, \
                 (char*)lds + 131072 + (buf) * 16384 + off); } }

#define MFMA_B(buf, kb) { \
    const unsigned short* W2b = lds + 65536 + (buf) * 8192; \
    __builtin_amdgcn_s_setprio(1); \
    { \
        s16x8 af[8], bfr[4]; \
        _Pragma("unroll") \
        for (int mi = 0; mi < 8; ++mi) { \
            int row = wm * 128 + mi * 16 + l15; \
            int slot = ((kb) * 4 + quad) ^ (row & 7); \
            af[mi] = *(const s16x8*)&lds[row * 256 + slot * 8]; } \
        _Pragma("unroll") \
        for (int ni = 0; ni < 4; ++ni) { \
            int row = wn * 64 + ni * 16 + l15; \
            int slot = quad ^ ((row >> 1) & 3); \
            bfr[ni] = *(const s16x8*)&W2b[row * 32 + slot * 8]; } \
        _Pragma("unroll") \
        for (int mi = 0; mi < 8; ++mi) \
            _Pragma("unroll") \
            for (int ni = 0; ni < 4; ++ni) \
                acc[mi][ni] = __builtin_amdgcn_mfma_f32_16x16x32_bf16( \
                    af[mi], bfr[ni], acc[mi][ni], 0, 0, 0); \
    } \
    __builtin_amdgcn_s_setprio(0); }

// stage-A step: stage(t+2) -> MFMA(t) -> pack(t+1)/load(t+2) POST-MFMA
#define STEP_A_MAIN(SB, SKB, AB, BB, PB, LK) { \
    B1STAGE(SB, SKB); \
    SCHED0(); \
    MFMA_A(AB, BB); \
    SCHED0(); \
    APACK(PB); \
    XLOAD(LK); \
    WAITV(12); \
    BAR(); \
    SCHED0(); }

#define STEP_B(tt) { \
    if ((tt) + 1 < 8) W2STAGE(1 - ((tt) & 1), (tt) + 1); \
    SCHED0(); \
    MFMA_B((tt) & 1, (tt)); \
    WAITV(0); \
    BAR(); \
    SCHED0(); }

    // ---------------- stage A prologue ------------------------------------
    XLOAD(0);
    SCHED0();
    B1STAGE(0, 0);
    B1STAGE(1, 1);
    SCHED0();
    APACK(0);              // waits x0 (vmcnt<=8); glds0/1 stay in flight
    XLOAD(64);
    WAITV(12);             // force glds0; keep glds1 + x1
    BAR();
    SCHED0();

    // ---------------- stage A: 8 k-steps, Bs ring-of-3 --------------------
    STEP_A_MAIN(2, 2, 0, 0, 1, 128);
    STEP_A_MAIN(0, 3, 1, 1, 0, 192);
    STEP_A_MAIN(1, 4, 0, 2, 1, 256);
    STEP_A_MAIN(2, 5, 1, 0, 0, 320);
    STEP_A_MAIN(0, 6, 0, 1, 1, 384);
    STEP_A_MAIN(1, 7, 1, 2, 0, 448);
    {   // step 6: no stage/load; pack slab 7
        MFMA_A(0, 0);
        SCHED0();
        APACK(1);
        WAITV(0);
        BAR();
        SCHED0();
    }
    {   // step 7
        MFMA_A(1, 1);
        WAITV(0);
        BAR();
        SCHED0();
    }

    // ---------------- transition: W2 prime + H1t write (overlay) ----------
    W2STAGE(0, 0);         // latency overlaps the H1t writes below
    SCHED0();
    #pragma unroll
    for (int mi = 0; mi < 8; ++mi)
        #pragma unroll
        for (int ni = 0; ni < 4; ++ni)
            #pragma unroll
            for (int r = 0; r < 4; ++r) {
                int row = wm * 128 + mi * 16 + quad * 4 + r;
                int col = wn * 64 + ni * 16 + l15;
                int slot = (col >> 3) ^ (row & 7);
                lds[row * 256 + slot * 8 + (col & 7)] = f2bf(lrelu(acc[mi][ni][r]));
            }
    WAITV(0);
    BAR();
    SCHED0();

    #pragma unroll
    for (int mi = 0; mi < 8; ++mi)
        #pragma unroll
        for (int ni = 0; ni < 4; ++ni)
            acc[mi][ni] = (f32x4){0.f, 0.f, 0.f, 0.f};

    // ---------------- stage B: 8 k-steps (BK=32) --------------------------
    STEP_B(0);
    STEP_B(1);
    STEP_B(2);
    STEP_B(3);
    STEP_B(4);
    STEP_B(5);
    STEP_B(6);
    STEP_B(7);

    // ---------------- W3-dot epilogue + fused stats -----------------------
    float* red = (float*)lds;            // [0:1024) floats, overlays dead H1t
    float* lsq = (float*)lds + 1024;     // ls[4], lq[4]
    float w3v[4];
    #pragma unroll
    for (int ni = 0; ni < 4; ++ni)
        w3v[ni] = W3[(size_t)p * HW + wn * 64 + ni * 16 + l15];
    float part[8][4];
    #pragma unroll
    for (int mi = 0; mi < 8; ++mi) {
        #pragma unroll
        for (int r = 0; r < 4; ++r) {
            float s = 0.f;
            #pragma unroll
            for (int ni = 0; ni < 4; ++ni)
                s += lrelu(acc[mi][ni][r]) * w3v[ni];
            part[mi][r] = s;
        }
    }
    #pragma unroll
    for (int off = 1; off < 16; off <<= 1)
        #pragma unroll
        for (int mi = 0; mi < 8; ++mi)
            #pragma unroll
            for (int r = 0; r < 4; ++r)
                part[mi][r] += __shfl_xor(part[mi][r], off);
    if (l15 == 0)
        #pragma unroll
        for (int mi = 0; mi < 8; ++mi)
            #pragma unroll
            for (int r = 0; r < 4; ++r)
                red[wn * 256 + wm * 128 + mi * 16 + quad * 4 + r] = part[mi][r];
    __syncthreads();
    if (t < 256) {
        float s = red[0 * 256 + t] + red[1 * 256 + t] + red[2 * 256 + t] + red[3 * 256 + t];
        float v = lrelu(s);
        pvec[(size_t)p * BATCH + bm0 + t] = v;
        float sq = v * v;
        #pragma unroll
        for (int off = 32; off; off >>= 1) {
            v  += __shfl_down(v, off);
            sq += __shfl_down(sq, off);
        }
        if (lane == 0) { lsq[wave] = v; lsq[4 + wave] = sq; }
    }
    __syncthreads();
    if (t == 0) {
        atomicAdd(accbuf + p,      lsq[0] + lsq[1] + lsq[2] + lsq[3]);
        atomicAdd(accbuf + 64 + p, lsq[4] + lsq[5] + lsq[6] + lsq[7]);
    }
#undef XLOAD
#undef APACK
#undef B1STAGE
#undef MFMA_A
#undef W2STAGE
#undef MFMA_B
#undef STEP_A_MAIN
#undef STEP_B
}

// ---------------------------------------------------------------------------
// Final head: derive mean/var from fused accumulators, closed-form norm,
// batchnorm-apply, covariates, linear, sigmoid.
// ---------------------------------------------------------------------------
__global__ __launch_bounds__(256)
void final_k(const float* __restrict__ pvec, const float* __restrict__ accbuf,
             const float* __restrict__ gamma, const float* __restrict__ beta,
             const float* __restrict__ x, const float* __restrict__ fc_w,
             const float* __restrict__ fc_b, float* __restrict__ out) {
    const int b = blockIdx.x * 256 + threadIdx.x;
    const float invB = 1.f / BATCH;
    float mean_[PW], inv_[PW];
    float nsq = 0.f;
    #pragma unroll
    for (int p = 0; p < PW; ++p) {
        float mean = accbuf[p] * invB;
        float var  = accbuf[64 + p] * invB - mean * mean;
        float inv  = rsqrtf(var + 1e-5f);
        mean_[p] = mean; inv_[p] = inv;
        float g = gamma[p], bt = beta[p];
        nsq += (float)BATCH * (g * g * var * inv * inv + bt * bt);
    }
    const float rn = rsqrtf(nsq);
    float acc = fc_b[0];
    #pragma unroll
    for (int p = 0; p < PW; ++p) {
        float pn = (pvec[(size_t)p * BATCH + b] - mean_[p]) * inv_[p] * gamma[p] + beta[p];
        acc += pn * rn * fc_w[p];
    }
    #pragma unroll
    for (int c = 0; c < COV; ++c)
        acc += x[(size_t)b * XROW + PW * NV + c] * fc_w[PW + c];
    out[b] = 1.f / (1.f + __expf(-acc));
}

// ---------------------------------------------------------------------------
extern "C" void kernel_launch(void* const* d_in, const int* in_sizes, int n_in,
                              void* d_out, int out_size, void* d_ws, size_t ws_size,
                              hipStream_t stream) {
    const float* x     = (const float*)d_in[0];
    const float* W1    = (const float*)d_in[1];
    const float* W2    = (const float*)d_in[2];
    const float* W3    = (const float*)d_in[3];
    const float* gamma = (const float*)d_in[4];
    const float* beta  = (const float*)d_in[5];
    const float* fc_w  = (const float*)d_in[6];
    const float* fc_b  = (const float*)d_in[7];
    float* out = (float*)d_out;

    char* ws = (char*)d_ws;
    size_t off = 0;
    unsigned short* W1I = (unsigned short*)(ws + off); off += (size_t)PW * NV * HW * 2;  // 16.78 MB
    unsigned short* W2I = (unsigned short*)(ws + off); off += (size_t)PW * HW * HW * 2;  //  8.39 MB
    float* pvec = (float*)(ws + off); off += (size_t)PW * BATCH * 4;                      //  0.5 MB
    float* accbuf = (float*)(ws + off); off += 256 * 4;                                   // sacc+qacc

    transpose_all<<<dim3(512 + 256), 256, 0, stream>>>(W1, W2, W1I, W2I, accbuf);
    pathway_fused<<<dim3(512), 512, 0, stream>>>(x, W1I, W2I, W3, pvec, accbuf);
    final_k<<<BATCH / 256, 256, 0, stream>>>(pvec, accbuf, gamma, beta, x, fc_w, fc_b, out);
}